// Round 4
// baseline (213.392 us; speedup 1.0000x reference)
//
#include <hip/hip_runtime.h>
#include <hip/hip_bf16.h>

// ---------- problem constants ----------
constexpr int Bb   = 2;
constexpr int Ss   = 2048;
constexpr int Dm   = 1024;
constexpr int Hh   = 16;
constexpr int Hd   = 64;
constexpr int Mtot = Bb * Ss;      // 4096
constexpr int NCH  = Ss / 64;      // 32 chunks of 64

typedef __bf16 bf16x8 __attribute__((ext_vector_type(8)));
typedef float  f32x4  __attribute__((ext_vector_type(4)));

__device__ __forceinline__ unsigned short f2bf(float f) {
  union { float f; unsigned u; } x; x.f = f;
  unsigned r = x.u + 0x7fffu + ((x.u >> 16) & 1u);   // RNE
  return (unsigned short)(r >> 16);
}

__device__ __forceinline__ float bf2f(unsigned short s) {
  union { unsigned u; float f; } x; x.u = ((unsigned)s) << 16;
  return x.f;
}

// ---------- transpose-convert W [K,N] f32 -> Wt [N,K] bf16 ----------
__global__ void k_transpose_conv(const float* __restrict__ W, unsigned short* __restrict__ Wt,
                                 int K, int N) {
  __shared__ float t[32][33];
  int n0 = blockIdx.x * 32, k0 = blockIdx.y * 32;
  int tx = threadIdx.x, ty = threadIdx.y;
#pragma unroll
  for (int j = 0; j < 32; j += 8)
    t[ty + j][tx] = W[(size_t)(k0 + ty + j) * N + n0 + tx];
  __syncthreads();
#pragma unroll
  for (int j = 0; j < 32; j += 8)
    Wt[(size_t)(n0 + ty + j) * K + k0 + tx] = f2bf(t[tx][ty + j]);
}

// ---------- n projection + x->bf16 convert ----------
// invn[b,h,s] = exp(-(x @ Wn + bn)); xb[m][k] = bf16(x)
__global__ void k_n_proj(const float* __restrict__ x, const float* __restrict__ Wn,
                         const float* __restrict__ bn, float* __restrict__ invn,
                         unsigned short* __restrict__ xb) {
  __shared__ float xl[4][1024];
  int tid = threadIdx.x, w = tid >> 6, lane = tid & 63;
  int row = blockIdx.x * 4 + w;                       // [0, 4096)
  const float4* x4 = (const float4*)(x + (size_t)row * Dm);
  ushort4* xb4 = (ushort4*)(xb + (size_t)row * Dm);
#pragma unroll
  for (int j = 0; j < 4; ++j) {
    float4 v = x4[j * 64 + lane];
    *(float4*)&xl[w][(j * 64 + lane) * 4] = v;
    ushort4 o;
    o.x = f2bf(v.x); o.y = f2bf(v.y); o.z = f2bf(v.z); o.w = f2bf(v.w);
    xb4[j * 64 + lane] = o;
  }
  __syncthreads();
  const float4* Wn4 = (const float4*)Wn;
  f32x4 sum = {0.f, 0.f, 0.f, 0.f};
#pragma unroll 4
  for (int j = 0; j < 64; ++j) {
    float xv = xl[w][j * 16 + (lane >> 2)];
    float4 wv = Wn4[j * 64 + lane];
    sum[0] += xv * wv.x; sum[1] += xv * wv.y; sum[2] += xv * wv.z; sum[3] += xv * wv.w;
  }
#pragma unroll
  for (int m = 4; m < 64; m <<= 1) {
    sum[0] += __shfl_xor(sum[0], m);
    sum[1] += __shfl_xor(sum[1], m);
    sum[2] += __shfl_xor(sum[2], m);
    sum[3] += __shfl_xor(sum[3], m);
  }
  if (lane < 4) {
    int b = row >> 11, s = row & 2047;
#pragma unroll
    for (int e = 0; e < 4; ++e) {
      int h = lane * 4 + e;
      float nv = sum[e] + bn[h];
      invn[((size_t)(b * Hh + h)) * Ss + s] = expf(-nv);
    }
  }
}

// ---------- streaming GEMM: A[M,K] bf16 x BT[N,K] bf16 (+bias), all operands from L2 ----------
// No LDS, no barriers. Block = 4 waves side-by-side in N (block tile 128M x 256N).
// Per wave: 128M x 64N output = 8 m-frags x 4 n-frags of 16x16, acc in f32.
// MODE 0: N=3072 fused projections: n<1024 -> q [bh,t,d]; 1024<=n<2048 -> k [bh,t,d] + kT [bh,d,t];
//         n>=2048 -> vT [bh,d,t].  bias: bias0=bqk for n<2048, bias1=bv else.
// MODE 2: N=1024, out0 = final f32 [m,n], bias0=bo.
template <int MODE, int Nn, int Kk>
__global__ __launch_bounds__(256, 2) void k_gemm_stream(
    const unsigned short* __restrict__ A, const unsigned short* __restrict__ BT,
    const float* __restrict__ bias0, const float* __restrict__ bias1,
    void* __restrict__ out0, void* __restrict__ out1,
    void* __restrict__ out2, void* __restrict__ out3) {
  int tid = threadIdx.x, w = tid >> 6, lane = tid & 63;
  // XCD-aware swizzle (nwg % 8 == 0 for both instantiations), n-outer decode so each
  // XCD's weight slice stays L2-resident.
  int gx = gridDim.x, gy = gridDim.y;
  int nwg = gx * gy;
  int bid = blockIdx.y * gx + blockIdx.x;
  int cpx = nwg >> 3;
  int swz = (bid & 7) * cpx + (bid >> 3);
  int bx = swz / gy, by = swz - bx * gy;
  int m0 = by * 128;
  int n0 = bx * 256 + w * 64;

  const unsigned short* Ab = A  + (size_t)(m0 + (lane & 15)) * Kk + (lane >> 4) * 8;
  const unsigned short* Bb = BT + (size_t)(n0 + (lane & 15)) * Kk + (lane >> 4) * 8;

  f32x4 acc[8][4] = {};
  for (int kt = 0; kt < (Kk >> 6); ++kt) {
#pragma unroll
    for (int ks = 0; ks < 2; ++ks) {
      bf16x8 af[8], bfr[4];
#pragma unroll
      for (int mf = 0; mf < 8; ++mf)
        af[mf] = *(const bf16x8*)(Ab + (size_t)mf * 16 * Kk + kt * 64 + ks * 32);
#pragma unroll
      for (int nf = 0; nf < 4; ++nf)
        bfr[nf] = *(const bf16x8*)(Bb + (size_t)nf * 16 * Kk + kt * 64 + ks * 32);
#pragma unroll
      for (int mf = 0; mf < 8; ++mf)
#pragma unroll
        for (int nf = 0; nf < 4; ++nf)
          acc[mf][nf] = __builtin_amdgcn_mfma_f32_16x16x32_bf16(af[mf], bfr[nf], acc[mf][nf], 0, 0, 0);
    }
  }

  // epilogue
#pragma unroll
  for (int mf = 0; mf < 8; ++mf) {
#pragma unroll
    for (int nf = 0; nf < 4; ++nf) {
      int n = n0 + nf * 16 + (lane & 15);
      int tbase = m0 + mf * 16 + (lane >> 4) * 4;
      if (MODE == 0) {
        int region = n >> 10;                 // wave-uniform (boundaries % 64 == 0)
        int h = (n >> 6) & 15, d = n & 63;
        int b = tbase >> 11, t = tbase & 2047;
        float bb = (region < 2) ? bias0[n] : bias1[n - 2048];
        if (region == 0) {
          unsigned short* qp = (unsigned short*)out0;
#pragma unroll
          for (int r = 0; r < 4; ++r)
            qp[(((size_t)(b * Hh + h)) * Ss + t + r) * Hd + d] = f2bf(acc[mf][nf][r] + bb);
        } else if (region == 1) {
          unsigned short* kp = (unsigned short*)out1;
#pragma unroll
          for (int r = 0; r < 4; ++r)
            kp[(((size_t)(b * Hh + h)) * Ss + t + r) * Hd + d] = f2bf(acc[mf][nf][r] + bb);
          ushort4 o;
          o.x = f2bf(acc[mf][nf][0] + bb);
          o.y = f2bf(acc[mf][nf][1] + bb);
          o.z = f2bf(acc[mf][nf][2] + bb);
          o.w = f2bf(acc[mf][nf][3] + bb);
          *(ushort4*)((unsigned short*)out2 + ((size_t)(b * Hh + h) * Hd + d) * Ss + t) = o;
        } else {
          ushort4 o;
          o.x = f2bf(acc[mf][nf][0] + bb);
          o.y = f2bf(acc[mf][nf][1] + bb);
          o.z = f2bf(acc[mf][nf][2] + bb);
          o.w = f2bf(acc[mf][nf][3] + bb);
          *(ushort4*)((unsigned short*)out3 + ((size_t)(b * Hh + h) * Hd + d) * Ss + t) = o;
        }
      } else {  // MODE 2
        float bb = bias0[n];
#pragma unroll
        for (int r = 0; r < 4; ++r)
          ((float*)out0)[(size_t)(tbase + r) * Nn + n] = acc[mf][nf][r] + bb;
      }
    }
  }
}

// ---------- pass A1: per-chunk gram  G_j[dv][d] = sum_{s in chunk j} v[s][dv]*k[s][d] ----------
// grid (NCH, 32 bh), 1 wave. Fully parallel, no barriers.
__global__ __launch_bounds__(64) void k_gram(
    const unsigned short* __restrict__ vT, const unsigned short* __restrict__ kT,
    unsigned short* __restrict__ G) {
  int lane = threadIdx.x;
  int j = blockIdx.x, bh = blockIdx.y;
  int t0 = j * 64;
  const unsigned short* vb = vT + (size_t)bh * Hd * Ss;
  const unsigned short* kb = kT + (size_t)bh * Hd * Ss;
  unsigned short* g = G + ((size_t)bh * NCH + j) * 4096;

  bf16x8 af[4][2], bfr[4][2];
#pragma unroll
  for (int mt = 0; mt < 4; ++mt)
#pragma unroll
    for (int ks = 0; ks < 2; ++ks) {
      af[mt][ks]  = *(const bf16x8*)(vb + (size_t)(mt * 16 + (lane & 15)) * Ss + t0 + ks * 32 + (lane >> 4) * 8);
      bfr[mt][ks] = *(const bf16x8*)(kb + (size_t)(mt * 16 + (lane & 15)) * Ss + t0 + ks * 32 + (lane >> 4) * 8);
    }
  f32x4 acc[4][4] = {};
#pragma unroll
  for (int mt = 0; mt < 4; ++mt)
#pragma unroll
    for (int nt = 0; nt < 4; ++nt)
#pragma unroll
      for (int ks = 0; ks < 2; ++ks)
        acc[mt][nt] = __builtin_amdgcn_mfma_f32_16x16x32_bf16(af[mt][ks], bfr[nt][ks], acc[mt][nt], 0, 0, 0);
#pragma unroll
  for (int mt = 0; mt < 4; ++mt)
#pragma unroll
    for (int nt = 0; nt < 4; ++nt)
#pragma unroll
      for (int r = 0; r < 4; ++r)
        g[(mt * 16 + (lane >> 4) * 4 + r) * 64 + nt * 16 + (lane & 15)] = f2bf(acc[mt][nt][r]);
}

// ---------- pass A2: exclusive prefix over chunks, per element ----------
// Sp[bh][j][e] = sum_{i<j} G[bh][i][e]   (f32 accum, bf16 in/out)
__global__ __launch_bounds__(256) void k_prefix(
    const unsigned short* __restrict__ G, unsigned short* __restrict__ Sp) {
  int gidx = blockIdx.x * 256 + threadIdx.x;   // 32 bh * 4096 elems
  int bh = gidx >> 12, e = gidx & 4095;
  const unsigned short* gp = G + (size_t)bh * NCH * 4096 + e;
  unsigned short* sp = Sp + (size_t)bh * NCH * 4096 + e;
  float acc = 0.f;
#pragma unroll 8
  for (int j = 0; j < NCH; ++j) {
    sp[(size_t)j * 4096] = f2bf(acc);
    acc += bf2f(gp[(size_t)j * 4096]);
  }
}

// ---------- pass B: per-chunk attention  ctx = (Q@S'^T + tril(QK^T)@V) * invn ----------
// grid (32 chunks, 32 bh), 256 threads (4 waves x 16 t-rows). No __syncthreads.
__global__ __launch_bounds__(256, 4) void k_chunk_attn(
    const unsigned short* __restrict__ q, const unsigned short* __restrict__ k,
    const unsigned short* __restrict__ vT, const unsigned short* __restrict__ Sp,
    const float* __restrict__ invn, unsigned short* __restrict__ ctx) {
  __shared__ __align__(16) unsigned short P[4 * 16 * 64];
  int tid = threadIdx.x, w = tid >> 6, lane = tid & 63;
  int j = blockIdx.x, bh = blockIdx.y;
  int t0 = j * 64;
  const unsigned short* qb = q + (size_t)bh * Ss * Hd;
  const unsigned short* kb = k + (size_t)bh * Ss * Hd;
  const unsigned short* vb = vT + (size_t)bh * Hd * Ss;
  const unsigned short* sp = Sp + ((size_t)bh * NCH + j) * 4096;

  bf16x8 qf[2];
#pragma unroll
  for (int ks = 0; ks < 2; ++ks)
    qf[ks] = *(const bf16x8*)(qb + (size_t)(t0 + w * 16 + (lane & 15)) * Hd + ks * 32 + (lane >> 4) * 8);

  // Q @ S'^T  (BT operand = S'[dv][d], d-contiguous)
  f32x4 acc[4] = {};
#pragma unroll
  for (int nt = 0; nt < 4; ++nt)
#pragma unroll
    for (int ks = 0; ks < 2; ++ks) {
      bf16x8 sf = *(const bf16x8*)(sp + (nt * 16 + (lane & 15)) * 64 + ks * 32 + (lane >> 4) * 8);
      acc[nt] = __builtin_amdgcn_mfma_f32_16x16x32_bf16(qf[ks], sf, acc[nt], 0, 0, 0);
    }

  // QK^T within chunk
  f32x4 sacc[4] = {};
#pragma unroll
  for (int nt = 0; nt < 4; ++nt)
#pragma unroll
    for (int ks = 0; ks < 2; ++ks) {
      bf16x8 kf = *(const bf16x8*)(kb + (size_t)(t0 + nt * 16 + (lane & 15)) * Hd + ks * 32 + (lane >> 4) * 8);
      sacc[nt] = __builtin_amdgcn_mfma_f32_16x16x32_bf16(qf[ks], kf, sacc[nt], 0, 0, 0);
    }

  // mask + bf16 P -> LDS (wave-local region, XOR-swizzled rows)
#pragma unroll
  for (int nt = 0; nt < 4; ++nt)
#pragma unroll
    for (int r = 0; r < 4; ++r) {
      int row = (lane >> 4) * 4 + r;
      int s_local = nt * 16 + (lane & 15);
      float vv = (s_local <= w * 16 + row) ? sacc[nt][r] : 0.f;
      int cb = s_local * 2;
      int byte = w * 2048 + row * 128 + (cb ^ ((row & 7) << 4));
      *(unsigned short*)((char*)P + byte) = f2bf(vv);
    }
  asm volatile("" ::: "memory");

  // P @ V
  bf16x8 pf[2];
#pragma unroll
  for (int ks = 0; ks < 2; ++ks) {
    int prow = lane & 15;
    int pcb = (ks * 32 + (lane >> 4) * 8) * 2;
    pf[ks] = *(const bf16x8*)((char*)P + w * 2048 + prow * 128 + (pcb ^ ((prow & 7) << 4)));
  }
#pragma unroll
  for (int dt = 0; dt < 4; ++dt)
#pragma unroll
    for (int ks = 0; ks < 2; ++ks) {
      bf16x8 vf = *(const bf16x8*)(vb + (size_t)(dt * 16 + (lane & 15)) * Ss + t0 + ks * 32 + (lane >> 4) * 8);
      acc[dt] = __builtin_amdgcn_mfma_f32_16x16x32_bf16(pf[ks], vf, acc[dt], 0, 0, 0);
    }

  // epilogue: scale by invn, write ctx [m][1024] bf16
  int b = bh >> 4, h = bh & 15;
  float sc[4];
#pragma unroll
  for (int r = 0; r < 4; ++r)
    sc[r] = invn[(size_t)bh * Ss + t0 + w * 16 + (lane >> 4) * 4 + r];
#pragma unroll
  for (int dt = 0; dt < 4; ++dt)
#pragma unroll
    for (int r = 0; r < 4; ++r) {
      int t = t0 + w * 16 + (lane >> 4) * 4 + r;
      size_t m = (size_t)b * Ss + t;
      ctx[m * Dm + h * Hd + dt * 16 + (lane & 15)] = f2bf(acc[dt][r] * sc[r]);
    }
}

// ---------- launch ----------
extern "C" void kernel_launch(void* const* d_in, const int* in_sizes, int n_in,
                              void* d_out, int out_size, void* d_ws, size_t ws_size,
                              hipStream_t stream) {
  const float* x   = (const float*)d_in[0];
  const float* Wqk = (const float*)d_in[1];
  const float* bqk = (const float*)d_in[2];
  const float* Wv  = (const float*)d_in[3];
  const float* bv  = (const float*)d_in[4];
  const float* Wn  = (const float*)d_in[5];
  const float* bn  = (const float*)d_in[6];
  const float* Wo  = (const float*)d_in[7];
  const float* bo  = (const float*)d_in[8];

  char* ws = (char*)d_ws;
  size_t off = 0;
  unsigned short* xb    = (unsigned short*)(ws + off); off += (size_t)Mtot * Dm * 2;          // 8 MB
  unsigned short* wprojT= (unsigned short*)(ws + off); off += (size_t)3072 * 1024 * 2;        // 6 MB
  unsigned short* woT   = (unsigned short*)(ws + off); off += (size_t)1024 * 1024 * 2;        // 2 MB
  unsigned short* qbuf  = (unsigned short*)(ws + off); off += (size_t)Bb * Hh * Ss * Hd * 2;  // 8 MB
  unsigned short* kbuf  = (unsigned short*)(ws + off); off += (size_t)Bb * Hh * Ss * Hd * 2;  // 8 MB
  unsigned short* ktbuf = (unsigned short*)(ws + off); off += (size_t)Bb * Hh * Ss * Hd * 2;  // 8 MB
  unsigned short* vbuf  = (unsigned short*)(ws + off); off += (size_t)Bb * Hh * Ss * Hd * 2;  // 8 MB
  float* invn           = (float*)(ws + off);          off += (size_t)Bb * Hh * Ss * 4;       // 256 KB
  unsigned short* G     = (unsigned short*)(ws + off); off += (size_t)Bb * Hh * NCH * 4096 * 2; // 8 MB
  unsigned short* Sp    = (unsigned short*)(ws + off); off += (size_t)Bb * Hh * NCH * 4096 * 2; // 8 MB
  unsigned short* ctx   = xb;  // alias: xb dead after fused projection GEMM

  // 1) weight transposes (bf16, [N][K])
  k_transpose_conv<<<dim3(2048 / 32, 1024 / 32), dim3(32, 8), 0, stream>>>(Wqk, wprojT, 1024, 2048);
  k_transpose_conv<<<dim3(1024 / 32, 1024 / 32), dim3(32, 8), 0, stream>>>(Wv, wprojT + (size_t)2048 * 1024, 1024, 1024);
  k_transpose_conv<<<dim3(1024 / 32, 1024 / 32), dim3(32, 8), 0, stream>>>(Wo, woT, 1024, 1024);

  // 2) n path + x conversion
  k_n_proj<<<Mtot / 4, 256, 0, stream>>>(x, Wn, bn, invn, xb);

  // 3) fused q/k/v projections (N = 3072), streaming GEMM
  k_gemm_stream<0, 3072, 1024><<<dim3(3072 / 256, Mtot / 128), 256, 0, stream>>>(
      xb, wprojT, bqk, bv, qbuf, kbuf, ktbuf, vbuf);

  // 4) attention = parallel gram + parallel prefix + per-chunk
  k_gram<<<dim3(NCH, Bb * Hh), 64, 0, stream>>>(vbuf, ktbuf, G);
  k_prefix<<<(Bb * Hh * 4096) / 256, 256, 0, stream>>>(G, Sp);
  k_chunk_attn<<<dim3(NCH, Bb * Hh), 256, 0, stream>>>(qbuf, kbuf, vbuf, Sp, invn, ctx);

  // 5) output projection -> f32 d_out, streaming GEMM
  k_gemm_stream<2, 1024, 1024><<<dim3(1024 / 256, Mtot / 128), 256, 0, stream>>>(
      ctx, woT, bo, nullptr, d_out, nullptr, nullptr, nullptr);
}

// Round 5
// 127.442 us; speedup vs baseline: 1.6744x; 1.6744x over previous
//
#include <hip/hip_runtime.h>
#include <hip/hip_bf16.h>

// ---------- problem constants ----------
constexpr int Bb   = 2;
constexpr int Ss   = 2048;
constexpr int Dm   = 1024;
constexpr int Hh   = 16;
constexpr int Hd   = 64;
constexpr int Mtot = Bb * Ss;      // 4096
constexpr int NCH  = Ss / 64;      // 32 chunks of 64

typedef __bf16 bf16x8 __attribute__((ext_vector_type(8)));
typedef float  f32x4  __attribute__((ext_vector_type(4)));
typedef __attribute__((address_space(1))) unsigned int u32_as1;
typedef __attribute__((address_space(3))) unsigned int u32_as3;

__device__ __forceinline__ void gload_lds16(const void* g, void* l) {
  __builtin_amdgcn_global_load_lds((const u32_as1*)g, (u32_as3*)l, 16, 0, 0);
}

__device__ __forceinline__ unsigned short f2bf(float f) {
  union { float f; unsigned u; } x; x.f = f;
  unsigned r = x.u + 0x7fffu + ((x.u >> 16) & 1u);   // RNE
  return (unsigned short)(r >> 16);
}

__device__ __forceinline__ float bf2f(unsigned short s) {
  union { unsigned u; float f; } x; x.u = ((unsigned)s) << 16;
  return x.f;
}

// ---------- transpose-convert W [K,N] f32 -> Wt [N,K] bf16 ----------
__global__ void k_transpose_conv(const float* __restrict__ W, unsigned short* __restrict__ Wt,
                                 int K, int N) {
  __shared__ float t[32][33];
  int n0 = blockIdx.x * 32, k0 = blockIdx.y * 32;
  int tx = threadIdx.x, ty = threadIdx.y;
#pragma unroll
  for (int j = 0; j < 32; j += 8)
    t[ty + j][tx] = W[(size_t)(k0 + ty + j) * N + n0 + tx];
  __syncthreads();
#pragma unroll
  for (int j = 0; j < 32; j += 8)
    Wt[(size_t)(n0 + ty + j) * K + k0 + tx] = f2bf(t[tx][ty + j]);
}

// ---------- n projection + x->bf16 convert ----------
__global__ void k_n_proj(const float* __restrict__ x, const float* __restrict__ Wn,
                         const float* __restrict__ bn, float* __restrict__ invn,
                         unsigned short* __restrict__ xb) {
  __shared__ float xl[4][1024];
  int tid = threadIdx.x, w = tid >> 6, lane = tid & 63;
  int row = blockIdx.x * 4 + w;                       // [0, 4096)
  const float4* x4 = (const float4*)(x + (size_t)row * Dm);
  ushort4* xb4 = (ushort4*)(xb + (size_t)row * Dm);
#pragma unroll
  for (int j = 0; j < 4; ++j) {
    float4 v = x4[j * 64 + lane];
    *(float4*)&xl[w][(j * 64 + lane) * 4] = v;
    ushort4 o;
    o.x = f2bf(v.x); o.y = f2bf(v.y); o.z = f2bf(v.z); o.w = f2bf(v.w);
    xb4[j * 64 + lane] = o;
  }
  __syncthreads();
  const float4* Wn4 = (const float4*)Wn;
  f32x4 sum = {0.f, 0.f, 0.f, 0.f};
#pragma unroll 4
  for (int j = 0; j < 64; ++j) {
    float xv = xl[w][j * 16 + (lane >> 2)];
    float4 wv = Wn4[j * 64 + lane];
    sum[0] += xv * wv.x; sum[1] += xv * wv.y; sum[2] += xv * wv.z; sum[3] += xv * wv.w;
  }
#pragma unroll
  for (int m = 4; m < 64; m <<= 1) {
    sum[0] += __shfl_xor(sum[0], m);
    sum[1] += __shfl_xor(sum[1], m);
    sum[2] += __shfl_xor(sum[2], m);
    sum[3] += __shfl_xor(sum[3], m);
  }
  if (lane < 4) {
    int b = row >> 11, s = row & 2047;
#pragma unroll
    for (int e = 0; e < 4; ++e) {
      int h = lane * 4 + e;
      float nv = sum[e] + bn[h];
      invn[((size_t)(b * Hh + h)) * Ss + s] = expf(-nv);
    }
  }
}

// ---------- pipelined 256x256 GEMM, BK=32, 4 LDS buffers, counted vmcnt ----------
// A[M,1024] bf16 row-major x BT[N,1024] bf16 row-major (+bias), 512 threads (8 waves, 2M x 4N).
// Per wave: 128M x 64N = 8 mf x 4 nf fragments. 2 phases per K-tile, 16 MFMA each.
// Stage tile t+3 during tile t (its buffer was last read in tile t-1 -> barrier-separated WAR-safe).
// vmcnt(8) once per tile: loads from tiles t-2,t-1 may be outstanding -> tile t's data (staged t-3) landed.
// LDS swizzle: chunk byte ^= (row&3)<<4 on stage-source and read (thread-constant, conflict-free).
// MODE 0: N=3072 fused proj -> q [bh,t,d] / k [bh,t,d] + kT [bh,d,t] / vT [bh,d,t]
// MODE 2: N=1024 -> out0 = f32 [m,1024] (+bo)
template <int MODE, int Nn>
__global__ __launch_bounds__(512, 2) void k_gemm8(
    const unsigned short* __restrict__ A, const unsigned short* __restrict__ BT,
    const float* __restrict__ bias0, const float* __restrict__ bias1,
    void* __restrict__ out0, void* __restrict__ out1,
    void* __restrict__ out2, void* __restrict__ out3) {
  constexpr int Kk = 1024;
  constexpr int NT = Kk / 32;            // 32 K-tiles
  __shared__ __align__(16) char lds[131072];   // 4 bufs x (A 16KB + B 16KB)
  int tid = threadIdx.x, w = tid >> 6, lane = tid & 63;
  int wm = w >> 2, wn = w & 3;

  // XCD-aware bijective swizzle (nwg % 8 == 0 for both grids), N-outer decode.
  int gx = gridDim.x, gy = gridDim.y;
  int nwg = gx * gy;
  int bid = blockIdx.y * gx + blockIdx.x;
  int cpx = nwg >> 3;
  int swz = (bid & 7) * cpx + (bid >> 3);
  int bx = swz / gy, by = swz % gy;
  int m0 = by * 256, n0 = bx * 256;

  // per-thread constant read offsets (swizzle folds into constants)
  int swzc = ((lane >> 4) * 16) ^ (((lane & 15) & 3) << 4);
  int abase = (wm * 128 + (lane & 15)) * 64 + swzc;            // + mf*1024 + buf*32768
  int bbase = 16384 + (wn * 64 + (lane & 15)) * 64 + swzc;     // + nf*1024 + buf*32768

  // staging source (thread-constant pattern)
  int srow0 = tid >> 2;                   // rows 0-127 (unit 0), +128 for unit 1
  int sc = ((tid & 3) * 16) ^ ((srow0 & 3) << 4);   // (row&3) identical for both units (+128)

  auto STAGE_A = [&](int tt, int bufS) {
#pragma unroll
    for (int i = 0; i < 2; ++i) {
      int row = i * 128 + srow0;
      gload_lds16(A + (size_t)(m0 + row) * Kk + tt * 32 + (sc >> 1),
                  lds + bufS * 32768 + i * 8192 + w * 1024);
    }
  };
  auto STAGE_B = [&](int tt, int bufS) {
#pragma unroll
    for (int i = 0; i < 2; ++i) {
      int row = i * 128 + srow0;
      gload_lds16(BT + (size_t)(n0 + row) * Kk + tt * 32 + (sc >> 1),
                  lds + bufS * 32768 + 16384 + i * 8192 + w * 1024);
    }
  };

  f32x4 acc[8][4] = {};

  // prologue: stage tiles 0,1,2 (12 loads/thread); tile 0 landed after vmcnt(8)
#pragma unroll
  for (int T = 0; T < 3; ++T) { STAGE_A(T, T); STAGE_B(T, T); }
  asm volatile("s_waitcnt vmcnt(8)" ::: "memory");
  __builtin_amdgcn_s_barrier();

#pragma unroll 4
  for (int t = 0; t < NT; ++t) {
    int buf = t & 3;
    int t3 = (t + 3) & (NT - 1);          // wraps at end: redundant but harmless
    int bufS = t3 & 3;
    const char* Lb = lds + buf * 32768;

    // ---- phase 0: mf 0-3 x nf 0-3 ----
    bf16x8 a0[4], b0[4];
#pragma unroll
    for (int mf = 0; mf < 4; ++mf) a0[mf] = *(const bf16x8*)(Lb + abase + mf * 1024);
#pragma unroll
    for (int nf = 0; nf < 4; ++nf) b0[nf] = *(const bf16x8*)(Lb + bbase + nf * 1024);
    STAGE_A(t3, bufS);
    __builtin_amdgcn_s_barrier();
    __builtin_amdgcn_s_setprio(1);
#pragma unroll
    for (int mf = 0; mf < 4; ++mf)
#pragma unroll
      for (int nf = 0; nf < 4; ++nf)
        acc[mf][nf] = __builtin_amdgcn_mfma_f32_16x16x32_bf16(a0[mf], b0[nf], acc[mf][nf], 0, 0, 0);
    __builtin_amdgcn_s_setprio(0);
    __builtin_amdgcn_s_barrier();

    // ---- phase 1: mf 4-7 x nf 0-3 (B frags reused) ----
    bf16x8 a1[4];
#pragma unroll
    for (int mf = 0; mf < 4; ++mf) a1[mf] = *(const bf16x8*)(Lb + abase + (mf + 4) * 1024);
    STAGE_B(t3, bufS);
    __builtin_amdgcn_s_barrier();
    __builtin_amdgcn_s_setprio(1);
#pragma unroll
    for (int mf = 0; mf < 4; ++mf)
#pragma unroll
      for (int nf = 0; nf < 4; ++nf)
        acc[mf + 4][nf] = __builtin_amdgcn_mfma_f32_16x16x32_bf16(a1[mf], b0[nf], acc[mf + 4][nf], 0, 0, 0);
    __builtin_amdgcn_s_setprio(0);
    asm volatile("s_waitcnt vmcnt(8)" ::: "memory");
    __builtin_amdgcn_s_barrier();
  }
  asm volatile("s_waitcnt vmcnt(0)" ::: "memory");

  // ---- epilogue ----
#pragma unroll
  for (int mf = 0; mf < 8; ++mf) {
#pragma unroll
    for (int nf = 0; nf < 4; ++nf) {
      int n = n0 + wn * 64 + nf * 16 + (lane & 15);
      int tbase = m0 + wm * 128 + mf * 16 + (lane >> 4) * 4;
      if (MODE == 0) {
        int region = n >> 10;             // wave-uniform
        int h = (n >> 6) & 15, d = n & 63;
        int b = tbase >> 11, t = tbase & 2047;
        float bb = (region < 2) ? bias0[n] : bias1[n - 2048];
        if (region == 0) {
          unsigned short* qp = (unsigned short*)out0;
#pragma unroll
          for (int r = 0; r < 4; ++r)
            qp[(((size_t)(b * Hh + h)) * Ss + t + r) * Hd + d] = f2bf(acc[mf][nf][r] + bb);
        } else if (region == 1) {
          unsigned short* kp = (unsigned short*)out1;
#pragma unroll
          for (int r = 0; r < 4; ++r)
            kp[(((size_t)(b * Hh + h)) * Ss + t + r) * Hd + d] = f2bf(acc[mf][nf][r] + bb);
          ushort4 o;
          o.x = f2bf(acc[mf][nf][0] + bb);
          o.y = f2bf(acc[mf][nf][1] + bb);
          o.z = f2bf(acc[mf][nf][2] + bb);
          o.w = f2bf(acc[mf][nf][3] + bb);
          *(ushort4*)((unsigned short*)out2 + ((size_t)(b * Hh + h) * Hd + d) * Ss + t) = o;
        } else {
          ushort4 o;
          o.x = f2bf(acc[mf][nf][0] + bb);
          o.y = f2bf(acc[mf][nf][1] + bb);
          o.z = f2bf(acc[mf][nf][2] + bb);
          o.w = f2bf(acc[mf][nf][3] + bb);
          *(ushort4*)((unsigned short*)out3 + ((size_t)(b * Hh + h) * Hd + d) * Ss + t) = o;
        }
      } else {  // MODE 2
        float bb = bias0[n];
#pragma unroll
        for (int r = 0; r < 4; ++r)
          ((float*)out0)[(size_t)(tbase + r) * Nn + n] = acc[mf][nf][r] + bb;
      }
    }
  }
}

// ---------- pass A1: per-chunk gram  G_j[dv][d] = sum_{s in chunk j} v[s][dv]*k[s][d] ----------
__global__ __launch_bounds__(64) void k_gram(
    const unsigned short* __restrict__ vT, const unsigned short* __restrict__ kT,
    unsigned short* __restrict__ G) {
  int lane = threadIdx.x;
  int j = blockIdx.x, bh = blockIdx.y;
  int t0 = j * 64;
  const unsigned short* vb = vT + (size_t)bh * Hd * Ss;
  const unsigned short* kb = kT + (size_t)bh * Hd * Ss;
  unsigned short* g = G + ((size_t)bh * NCH + j) * 4096;

  bf16x8 af[4][2], bfr[4][2];
#pragma unroll
  for (int mt = 0; mt < 4; ++mt)
#pragma unroll
    for (int ks = 0; ks < 2; ++ks) {
      af[mt][ks]  = *(const bf16x8*)(vb + (size_t)(mt * 16 + (lane & 15)) * Ss + t0 + ks * 32 + (lane >> 4) * 8);
      bfr[mt][ks] = *(const bf16x8*)(kb + (size_t)(mt * 16 + (lane & 15)) * Ss + t0 + ks * 32 + (lane >> 4) * 8);
    }
  f32x4 acc[4][4] = {};
#pragma unroll
  for (int mt = 0; mt < 4; ++mt)
#pragma unroll
    for (int nt = 0; nt < 4; ++nt)
#pragma unroll
      for (int ks = 0; ks < 2; ++ks)
        acc[mt][nt] = __builtin_amdgcn_mfma_f32_16x16x32_bf16(af[mt][ks], bfr[nt][ks], acc[mt][nt], 0, 0, 0);
#pragma unroll
  for (int mt = 0; mt < 4; ++mt)
#pragma unroll
    for (int nt = 0; nt < 4; ++nt)
#pragma unroll
      for (int r = 0; r < 4; ++r)
        g[(mt * 16 + (lane >> 4) * 4 + r) * 64 + nt * 16 + (lane & 15)] = f2bf(acc[mt][nt][r]);
}

// ---------- pass A2: exclusive prefix over chunks ----------
__global__ __launch_bounds__(256) void k_prefix(
    const unsigned short* __restrict__ G, unsigned short* __restrict__ Sp) {
  int gidx = blockIdx.x * 256 + threadIdx.x;   // 32 bh * 4096 elems
  int bh = gidx >> 12, e = gidx & 4095;
  const unsigned short* gp = G + (size_t)bh * NCH * 4096 + e;
  unsigned short* sp = Sp + (size_t)bh * NCH * 4096 + e;
  float acc = 0.f;
#pragma unroll 8
  for (int j = 0; j < NCH; ++j) {
    sp[(size_t)j * 4096] = f2bf(acc);
    acc += bf2f(gp[(size_t)j * 4096]);
  }
}

// ---------- pass B: per-chunk attention  ctx = (Q@S'^T + tril(QK^T)@V) * invn ----------
__global__ __launch_bounds__(256, 4) void k_chunk_attn(
    const unsigned short* __restrict__ q, const unsigned short* __restrict__ k,
    const unsigned short* __restrict__ vT, const unsigned short* __restrict__ Sp,
    const float* __restrict__ invn, unsigned short* __restrict__ ctx) {
  __shared__ __align__(16) unsigned short P[4 * 16 * 64];
  int tid = threadIdx.x, w = tid >> 6, lane = tid & 63;
  int j = blockIdx.x, bh = blockIdx.y;
  int t0 = j * 64;
  const unsigned short* qb = q + (size_t)bh * Ss * Hd;
  const unsigned short* kb = k + (size_t)bh * Ss * Hd;
  const unsigned short* vb = vT + (size_t)bh * Hd * Ss;
  const unsigned short* sp = Sp + ((size_t)bh * NCH + j) * 4096;

  bf16x8 qf[2];
#pragma unroll
  for (int ks = 0; ks < 2; ++ks)
    qf[ks] = *(const bf16x8*)(qb + (size_t)(t0 + w * 16 + (lane & 15)) * Hd + ks * 32 + (lane >> 4) * 8);

  f32x4 acc[4] = {};
#pragma unroll
  for (int nt = 0; nt < 4; ++nt)
#pragma unroll
    for (int ks = 0; ks < 2; ++ks) {
      bf16x8 sf = *(const bf16x8*)(sp + (nt * 16 + (lane & 15)) * 64 + ks * 32 + (lane >> 4) * 8);
      acc[nt] = __builtin_amdgcn_mfma_f32_16x16x32_bf16(qf[ks], sf, acc[nt], 0, 0, 0);
    }

  f32x4 sacc[4] = {};
#pragma unroll
  for (int nt = 0; nt < 4; ++nt)
#pragma unroll
    for (int ks = 0; ks < 2; ++ks) {
      bf16x8 kf = *(const bf16x8*)(kb + (size_t)(t0 + nt * 16 + (lane & 15)) * Hd + ks * 32 + (lane >> 4) * 8);
      sacc[nt] = __builtin_amdgcn_mfma_f32_16x16x32_bf16(qf[ks], kf, sacc[nt], 0, 0, 0);
    }

#pragma unroll
  for (int nt = 0; nt < 4; ++nt)
#pragma unroll
    for (int r = 0; r < 4; ++r) {
      int row = (lane >> 4) * 4 + r;
      int s_local = nt * 16 + (lane & 15);
      float vv = (s_local <= w * 16 + row) ? sacc[nt][r] : 0.f;
      int cb = s_local * 2;
      int byte = w * 2048 + row * 128 + (cb ^ ((row & 7) << 4));
      *(unsigned short*)((char*)P + byte) = f2bf(vv);
    }
  asm volatile("" ::: "memory");

  bf16x8 pf[2];
#pragma unroll
  for (int ks = 0; ks < 2; ++ks) {
    int prow = lane & 15;
    int pcb = (ks * 32 + (lane >> 4) * 8) * 2;
    pf[ks] = *(const bf16x8*)((char*)P + w * 2048 + prow * 128 + (pcb ^ ((prow & 7) << 4)));
  }
#pragma unroll
  for (int dt = 0; dt < 4; ++dt)
#pragma unroll
    for (int ks = 0; ks < 2; ++ks) {
      bf16x8 vf = *(const bf16x8*)(vb + (size_t)(dt * 16 + (lane & 15)) * Ss + t0 + ks * 32 + (lane >> 4) * 8);
      acc[dt] = __builtin_amdgcn_mfma_f32_16x16x32_bf16(pf[ks], vf, acc[dt], 0, 0, 0);
    }

  int b = bh >> 4, h = bh & 15;
  float sc[4];
#pragma unroll
  for (int r = 0; r < 4; ++r)
    sc[r] = invn[(size_t)bh * Ss + t0 + w * 16 + (lane >> 4) * 4 + r];
#pragma unroll
  for (int dt = 0; dt < 4; ++dt)
#pragma unroll
    for (int r = 0; r < 4; ++r) {
      int t = t0 + w * 16 + (lane >> 4) * 4 + r;
      size_t m = (size_t)b * Ss + t;
      ctx[m * Dm + h * Hd + dt * 16 + (lane & 15)] = f2bf(acc[dt][r] * sc[r]);
    }
}

// ---------- launch ----------
extern "C" void kernel_launch(void* const* d_in, const int* in_sizes, int n_in,
                              void* d_out, int out_size, void* d_ws, size_t ws_size,
                              hipStream_t stream) {
  const float* x   = (const float*)d_in[0];
  const float* Wqk = (const float*)d_in[1];
  const float* bqk = (const float*)d_in[2];
  const float* Wv  = (const float*)d_in[3];
  const float* bv  = (const float*)d_in[4];
  const float* Wn  = (const float*)d_in[5];
  const float* bn  = (const float*)d_in[6];
  const float* Wo  = (const float*)d_in[7];
  const float* bo  = (const float*)d_in[8];

  char* ws = (char*)d_ws;
  size_t off = 0;
  unsigned short* xb    = (unsigned short*)(ws + off); off += (size_t)Mtot * Dm * 2;          // 8 MB
  unsigned short* wprojT= (unsigned short*)(ws + off); off += (size_t)3072 * 1024 * 2;        // 6 MB
  unsigned short* woT   = (unsigned short*)(ws + off); off += (size_t)1024 * 1024 * 2;        // 2 MB
  unsigned short* qbuf  = (unsigned short*)(ws + off); off += (size_t)Bb * Hh * Ss * Hd * 2;  // 8 MB
  unsigned short* kbuf  = (unsigned short*)(ws + off); off += (size_t)Bb * Hh * Ss * Hd * 2;  // 8 MB
  unsigned short* ktbuf = (unsigned short*)(ws + off); off += (size_t)Bb * Hh * Ss * Hd * 2;  // 8 MB
  unsigned short* vbuf  = (unsigned short*)(ws + off); off += (size_t)Bb * Hh * Ss * Hd * 2;  // 8 MB
  float* invn           = (float*)(ws + off);          off += (size_t)Bb * Hh * Ss * 4;       // 256 KB
  unsigned short* G     = (unsigned short*)(ws + off); off += (size_t)Bb * Hh * NCH * 4096 * 2; // 8 MB
  unsigned short* Sp    = (unsigned short*)(ws + off); off += (size_t)Bb * Hh * NCH * 4096 * 2; // 8 MB
  unsigned short* ctx   = xb;  // alias: xb dead after fused projection GEMM

  // 1) weight transposes (bf16, [N][K])
  k_transpose_conv<<<dim3(2048 / 32, 1024 / 32), dim3(32, 8), 0, stream>>>(Wqk, wprojT, 1024, 2048);
  k_transpose_conv<<<dim3(1024 / 32, 1024 / 32), dim3(32, 8), 0, stream>>>(Wv, wprojT + (size_t)2048 * 1024, 1024, 1024);
  k_transpose_conv<<<dim3(1024 / 32, 1024 / 32), dim3(32, 8), 0, stream>>>(Wo, woT, 1024, 1024);

  // 2) n path + x conversion
  k_n_proj<<<Mtot / 4, 256, 0, stream>>>(x, Wn, bn, invn, xb);

  // 3) fused q/k/v projections (N = 3072), 8-phase pipelined GEMM (grid 12x16 = 192)
  k_gemm8<0, 3072><<<dim3(3072 / 256, Mtot / 256), 512, 0, stream>>>(
      xb, wprojT, bqk, bv, qbuf, kbuf, ktbuf, vbuf);

  // 4) attention = parallel gram + parallel prefix + per-chunk
  k_gram<<<dim3(NCH, Bb * Hh), 64, 0, stream>>>(vbuf, ktbuf, G);
  k_prefix<<<(Bb * Hh * 4096) / 256, 256, 0, stream>>>(G, Sp);
  k_chunk_attn<<<dim3(NCH, Bb * Hh), 256, 0, stream>>>(qbuf, kbuf, vbuf, Sp, invn, ctx);

  // 5) output projection -> f32 d_out (grid 4x16 = 64)
  k_gemm8<2, 1024><<<dim3(1024 / 256, Mtot / 256), 512, 0, stream>>>(
      ctx, woT, bo, nullptr, d_out, nullptr, nullptr, nullptr);
}

// Round 6
// 112.573 us; speedup vs baseline: 1.8956x; 1.1321x over previous
//
#include <hip/hip_runtime.h>
#include <hip/hip_bf16.h>

// ---------- problem constants ----------
constexpr int Bb   = 2;
constexpr int Ss   = 2048;
constexpr int Dm   = 1024;
constexpr int Hh   = 16;
constexpr int Hd   = 64;
constexpr int Mtot = Bb * Ss;      // 4096
constexpr int NCH  = Ss / 64;      // 32 chunks of 64

typedef __bf16 bf16x8 __attribute__((ext_vector_type(8)));
typedef float  f32x4  __attribute__((ext_vector_type(4)));
typedef __attribute__((address_space(1))) unsigned int u32_as1;
typedef __attribute__((address_space(3))) unsigned int u32_as3;

__device__ __forceinline__ void gload_lds16(const void* g, void* l) {
  __builtin_amdgcn_global_load_lds((const u32_as1*)g, (u32_as3*)l, 16, 0, 0);
}

__device__ __forceinline__ unsigned short f2bf(float f) {
  union { float f; unsigned u; } x; x.f = f;
  unsigned r = x.u + 0x7fffu + ((x.u >> 16) & 1u);   // RNE
  return (unsigned short)(r >> 16);
}

__device__ __forceinline__ float bf2f(unsigned short s) {
  union { unsigned u; float f; } x; x.u = ((unsigned)s) << 16;
  return x.f;
}

// ---------- transpose-convert W [K,N] f32 -> Wt [N,K] bf16 ----------
__global__ void k_transpose_conv(const float* __restrict__ W, unsigned short* __restrict__ Wt,
                                 int K, int N) {
  __shared__ float t[32][33];
  int n0 = blockIdx.x * 32, k0 = blockIdx.y * 32;
  int tx = threadIdx.x, ty = threadIdx.y;
#pragma unroll
  for (int j = 0; j < 32; j += 8)
    t[ty + j][tx] = W[(size_t)(k0 + ty + j) * N + n0 + tx];
  __syncthreads();
#pragma unroll
  for (int j = 0; j < 32; j += 8)
    Wt[(size_t)(n0 + ty + j) * K + k0 + tx] = f2bf(t[tx][ty + j]);
}

// ---------- n projection + x->bf16 convert ----------
// invn[b,h,s] = exp(-(x @ Wn + bn)); xb[m][k] = bf16(x)
__global__ void k_n_proj(const float* __restrict__ x, const float* __restrict__ Wn,
                         const float* __restrict__ bn, float* __restrict__ invn,
                         unsigned short* __restrict__ xb) {
  __shared__ float xl[4][1024];
  int tid = threadIdx.x, w = tid >> 6, lane = tid & 63;
  int row = blockIdx.x * 4 + w;                       // [0, 4096)
  const float4* x4 = (const float4*)(x + (size_t)row * Dm);
  ushort4* xb4 = (ushort4*)(xb + (size_t)row * Dm);
#pragma unroll
  for (int j = 0; j < 4; ++j) {
    float4 v = x4[j * 64 + lane];
    *(float4*)&xl[w][(j * 64 + lane) * 4] = v;
    ushort4 o;
    o.x = f2bf(v.x); o.y = f2bf(v.y); o.z = f2bf(v.z); o.w = f2bf(v.w);
    xb4[j * 64 + lane] = o;
  }
  __syncthreads();
  const float4* Wn4 = (const float4*)Wn;
  f32x4 sum = {0.f, 0.f, 0.f, 0.f};
#pragma unroll 4
  for (int j = 0; j < 64; ++j) {
    float xv = xl[w][j * 16 + (lane >> 2)];
    float4 wv = Wn4[j * 64 + lane];
    sum[0] += xv * wv.x; sum[1] += xv * wv.y; sum[2] += xv * wv.z; sum[3] += xv * wv.w;
  }
#pragma unroll
  for (int m = 4; m < 64; m <<= 1) {
    sum[0] += __shfl_xor(sum[0], m);
    sum[1] += __shfl_xor(sum[1], m);
    sum[2] += __shfl_xor(sum[2], m);
    sum[3] += __shfl_xor(sum[3], m);
  }
  if (lane < 4) {
    int b = row >> 11, s = row & 2047;
#pragma unroll
    for (int e = 0; e < 4; ++e) {
      int h = lane * 4 + e;
      float nv = sum[e] + bn[h];
      invn[((size_t)(b * Hh + h)) * Ss + s] = expf(-nv);
    }
  }
}

// ---------- fused projection GEMM (m97 structure, proven): A[M,K] x BT[N,K] ----------
// N=3072: n<1024 -> q [bh,t,d]; 1024<=n<2048 -> k [bh,t,d] + kT [bh,d,t]; n>=2048 -> vT [bh,d,t]
__global__ __launch_bounds__(256, 2) void k_gemm_proj(
    const unsigned short* __restrict__ A, const unsigned short* __restrict__ BT,
    const float* __restrict__ bias0, const float* __restrict__ bias1,
    void* __restrict__ out0, void* __restrict__ out1, void* __restrict__ out2,
    void* __restrict__ out3, int M, int N, int K) {
  __shared__ __align__(16) unsigned short As[128 * 64];
  __shared__ __align__(16) unsigned short Bs[128 * 64];
  int tid = threadIdx.x, w = tid >> 6, lane = tid & 63;
  int m0 = blockIdx.y * 128, n0 = blockIdx.x * 128;
  int wm = w >> 1, wn = w & 1;
  f32x4 acc[4][4] = {};

  for (int kt = 0; kt < (K >> 6); ++kt) {
#pragma unroll
    for (int i = 0; i < 4; ++i) {
      int lin = i * 2048 + w * 512 + lane * 8;
      int r = lin >> 6, c = lin & 63;
      gload_lds16(A + (size_t)(m0 + r) * K + kt * 64 + c, As + i * 2048 + w * 512);
    }
#pragma unroll
    for (int i = 0; i < 4; ++i) {
      int lin = i * 2048 + w * 512 + lane * 8;
      int r = lin >> 6, c = lin & 63;
      gload_lds16(BT + (size_t)(n0 + r) * K + kt * 64 + c, Bs + i * 2048 + w * 512);
    }
    __syncthreads();
#pragma unroll
    for (int ks = 0; ks < 2; ++ks) {
      bf16x8 af[4], bfr[4];
#pragma unroll
      for (int mt = 0; mt < 4; ++mt)
        af[mt] = *(const bf16x8*)(As + (wm * 64 + mt * 16 + (lane & 15)) * 64 + ks * 32 + (lane >> 4) * 8);
#pragma unroll
      for (int nt = 0; nt < 4; ++nt)
        bfr[nt] = *(const bf16x8*)(Bs + (wn * 64 + nt * 16 + (lane & 15)) * 64 + ks * 32 + (lane >> 4) * 8);
#pragma unroll
      for (int mt = 0; mt < 4; ++mt)
#pragma unroll
        for (int nt = 0; nt < 4; ++nt)
          acc[mt][nt] = __builtin_amdgcn_mfma_f32_16x16x32_bf16(af[mt], bfr[nt], acc[mt][nt], 0, 0, 0);
    }
    __syncthreads();
  }

#pragma unroll
  for (int mt = 0; mt < 4; ++mt) {
#pragma unroll
    for (int nt = 0; nt < 4; ++nt) {
      int n = n0 + wn * 64 + nt * 16 + (lane & 15);
      int tbase = m0 + wm * 64 + mt * 16 + (lane >> 4) * 4;
      int region = n >> 10;                 // wave-uniform (boundaries % 128 == 0)
      int h = (n >> 6) & 15, d = n & 63;
      int b = tbase >> 11, t = tbase & 2047;
      float bb = (region < 2) ? bias0[n] : bias1[n - 2048];
      if (region == 0) {
        unsigned short* qp = (unsigned short*)out0;
#pragma unroll
        for (int r = 0; r < 4; ++r)
          qp[(((size_t)(b * Hh + h)) * Ss + t + r) * Hd + d] = f2bf(acc[mt][nt][r] + bb);
      } else if (region == 1) {
        unsigned short* kp = (unsigned short*)out1;
#pragma unroll
        for (int r = 0; r < 4; ++r)
          kp[(((size_t)(b * Hh + h)) * Ss + t + r) * Hd + d] = f2bf(acc[mt][nt][r] + bb);
        ushort4 o;
        o.x = f2bf(acc[mt][nt][0] + bb);
        o.y = f2bf(acc[mt][nt][1] + bb);
        o.z = f2bf(acc[mt][nt][2] + bb);
        o.w = f2bf(acc[mt][nt][3] + bb);
        *(ushort4*)((unsigned short*)out2 + ((size_t)(b * Hh + h) * Hd + d) * Ss + t) = o;
      } else {
        ushort4 o;
        o.x = f2bf(acc[mt][nt][0] + bb);
        o.y = f2bf(acc[mt][nt][1] + bb);
        o.z = f2bf(acc[mt][nt][2] + bb);
        o.w = f2bf(acc[mt][nt][3] + bb);
        *(ushort4*)((unsigned short*)out3 + ((size_t)(b * Hh + h) * Hd + d) * Ss + t) = o;
      }
    }
  }
}

// ---------- output GEMM: 64x128 tile for occupancy (512 blocks, 2/CU) ----------
// out[m][1024] f32 = ctx[m][k] @ WoT[n][k] + bo
__global__ __launch_bounds__(256, 4) void k_gemm_o(
    const unsigned short* __restrict__ A, const unsigned short* __restrict__ BT,
    const float* __restrict__ bias, float* __restrict__ out) {
  constexpr int K = 1024, N = 1024;
  __shared__ __align__(16) unsigned short As[64 * 64];
  __shared__ __align__(16) unsigned short Bs[128 * 64];
  int tid = threadIdx.x, w = tid >> 6, lane = tid & 63;
  int m0 = blockIdx.y * 64, n0 = blockIdx.x * 128;
  int wm = w >> 1, wn = w & 1;    // waves: 2 over M(32 each), 2 over N(64 each)
  f32x4 acc[2][4] = {};

  for (int kt = 0; kt < (K >> 6); ++kt) {
#pragma unroll
    for (int i = 0; i < 2; ++i) {
      int lin = i * 2048 + w * 512 + lane * 8;
      int r = lin >> 6, c = lin & 63;
      gload_lds16(A + (size_t)(m0 + r) * K + kt * 64 + c, As + i * 2048 + w * 512);
    }
#pragma unroll
    for (int i = 0; i < 4; ++i) {
      int lin = i * 2048 + w * 512 + lane * 8;
      int r = lin >> 6, c = lin & 63;
      gload_lds16(BT + (size_t)(n0 + r) * K + kt * 64 + c, Bs + i * 2048 + w * 512);
    }
    __syncthreads();
#pragma unroll
    for (int ks = 0; ks < 2; ++ks) {
      bf16x8 af[2], bfr[4];
#pragma unroll
      for (int mt = 0; mt < 2; ++mt)
        af[mt] = *(const bf16x8*)(As + (wm * 32 + mt * 16 + (lane & 15)) * 64 + ks * 32 + (lane >> 4) * 8);
#pragma unroll
      for (int nt = 0; nt < 4; ++nt)
        bfr[nt] = *(const bf16x8*)(Bs + (wn * 64 + nt * 16 + (lane & 15)) * 64 + ks * 32 + (lane >> 4) * 8);
#pragma unroll
      for (int mt = 0; mt < 2; ++mt)
#pragma unroll
        for (int nt = 0; nt < 4; ++nt)
          acc[mt][nt] = __builtin_amdgcn_mfma_f32_16x16x32_bf16(af[mt], bfr[nt], acc[mt][nt], 0, 0, 0);
    }
    __syncthreads();
  }

#pragma unroll
  for (int mt = 0; mt < 2; ++mt) {
#pragma unroll
    for (int nt = 0; nt < 4; ++nt) {
      int n = n0 + wn * 64 + nt * 16 + (lane & 15);
      int m = m0 + wm * 32 + mt * 16 + (lane >> 4) * 4;
      float bb = bias[n];
#pragma unroll
      for (int r = 0; r < 4; ++r)
        out[(size_t)(m + r) * N + n] = acc[mt][nt][r] + bb;
    }
  }
}

// ---------- pass A1: per-chunk gram  G_j[dv][d] = sum_{s in chunk j} v[s][dv]*k[s][d] ----------
__global__ __launch_bounds__(64) void k_gram(
    const unsigned short* __restrict__ vT, const unsigned short* __restrict__ kT,
    unsigned short* __restrict__ G) {
  int lane = threadIdx.x;
  int j = blockIdx.x, bh = blockIdx.y;
  int t0 = j * 64;
  const unsigned short* vb = vT + (size_t)bh * Hd * Ss;
  const unsigned short* kb = kT + (size_t)bh * Hd * Ss;
  unsigned short* g = G + ((size_t)bh * NCH + j) * 4096;

  bf16x8 af[4][2], bfr[4][2];
#pragma unroll
  for (int mt = 0; mt < 4; ++mt)
#pragma unroll
    for (int ks = 0; ks < 2; ++ks) {
      af[mt][ks]  = *(const bf16x8*)(vb + (size_t)(mt * 16 + (lane & 15)) * Ss + t0 + ks * 32 + (lane >> 4) * 8);
      bfr[mt][ks] = *(const bf16x8*)(kb + (size_t)(mt * 16 + (lane & 15)) * Ss + t0 + ks * 32 + (lane >> 4) * 8);
    }
  f32x4 acc[4][4] = {};
#pragma unroll
  for (int mt = 0; mt < 4; ++mt)
#pragma unroll
    for (int nt = 0; nt < 4; ++nt)
#pragma unroll
      for (int ks = 0; ks < 2; ++ks)
        acc[mt][nt] = __builtin_amdgcn_mfma_f32_16x16x32_bf16(af[mt][ks], bfr[nt][ks], acc[mt][nt], 0, 0, 0);
#pragma unroll
  for (int mt = 0; mt < 4; ++mt)
#pragma unroll
    for (int nt = 0; nt < 4; ++nt)
#pragma unroll
      for (int r = 0; r < 4; ++r)
        g[(mt * 16 + (lane >> 4) * 4 + r) * 64 + nt * 16 + (lane & 15)] = f2bf(acc[mt][nt][r]);
}

// ---------- pass A2: exclusive prefix over chunks ----------
__global__ __launch_bounds__(256) void k_prefix(
    const unsigned short* __restrict__ G, unsigned short* __restrict__ Sp) {
  int gidx = blockIdx.x * 256 + threadIdx.x;   // 32 bh * 4096 elems
  int bh = gidx >> 12, e = gidx & 4095;
  const unsigned short* gp = G + (size_t)bh * NCH * 4096 + e;
  unsigned short* sp = Sp + (size_t)bh * NCH * 4096 + e;
  float acc = 0.f;
#pragma unroll 8
  for (int j = 0; j < NCH; ++j) {
    sp[(size_t)j * 4096] = f2bf(acc);
    acc += bf2f(gp[(size_t)j * 4096]);
  }
}

// ---------- pass B: per-chunk attention  ctx = (Q@S'^T + tril(QK^T)@V) * invn ----------
__global__ __launch_bounds__(256, 4) void k_chunk_attn(
    const unsigned short* __restrict__ q, const unsigned short* __restrict__ k,
    const unsigned short* __restrict__ vT, const unsigned short* __restrict__ Sp,
    const float* __restrict__ invn, unsigned short* __restrict__ ctx) {
  __shared__ __align__(16) unsigned short P[4 * 16 * 64];
  int tid = threadIdx.x, w = tid >> 6, lane = tid & 63;
  int j = blockIdx.x, bh = blockIdx.y;
  int t0 = j * 64;
  const unsigned short* qb = q + (size_t)bh * Ss * Hd;
  const unsigned short* kb = k + (size_t)bh * Ss * Hd;
  const unsigned short* vb = vT + (size_t)bh * Hd * Ss;
  const unsigned short* sp = Sp + ((size_t)bh * NCH + j) * 4096;

  bf16x8 qf[2];
#pragma unroll
  for (int ks = 0; ks < 2; ++ks)
    qf[ks] = *(const bf16x8*)(qb + (size_t)(t0 + w * 16 + (lane & 15)) * Hd + ks * 32 + (lane >> 4) * 8);

  f32x4 acc[4] = {};
#pragma unroll
  for (int nt = 0; nt < 4; ++nt)
#pragma unroll
    for (int ks = 0; ks < 2; ++ks) {
      bf16x8 sf = *(const bf16x8*)(sp + (nt * 16 + (lane & 15)) * 64 + ks * 32 + (lane >> 4) * 8);
      acc[nt] = __builtin_amdgcn_mfma_f32_16x16x32_bf16(qf[ks], sf, acc[nt], 0, 0, 0);
    }

  f32x4 sacc[4] = {};
#pragma unroll
  for (int nt = 0; nt < 4; ++nt)
#pragma unroll
    for (int ks = 0; ks < 2; ++ks) {
      bf16x8 kf = *(const bf16x8*)(kb + (size_t)(t0 + nt * 16 + (lane & 15)) * Hd + ks * 32 + (lane >> 4) * 8);
      sacc[nt] = __builtin_amdgcn_mfma_f32_16x16x32_bf16(qf[ks], kf, sacc[nt], 0, 0, 0);
    }

#pragma unroll
  for (int nt = 0; nt < 4; ++nt)
#pragma unroll
    for (int r = 0; r < 4; ++r) {
      int row = (lane >> 4) * 4 + r;
      int s_local = nt * 16 + (lane & 15);
      float vv = (s_local <= w * 16 + row) ? sacc[nt][r] : 0.f;
      int cb = s_local * 2;
      int byte = w * 2048 + row * 128 + (cb ^ ((row & 7) << 4));
      *(unsigned short*)((char*)P + byte) = f2bf(vv);
    }
  asm volatile("" ::: "memory");

  bf16x8 pf[2];
#pragma unroll
  for (int ks = 0; ks < 2; ++ks) {
    int prow = lane & 15;
    int pcb = (ks * 32 + (lane >> 4) * 8) * 2;
    pf[ks] = *(const bf16x8*)((char*)P + w * 2048 + prow * 128 + (pcb ^ ((prow & 7) << 4)));
  }
#pragma unroll
  for (int dt = 0; dt < 4; ++dt)
#pragma unroll
    for (int ks = 0; ks < 2; ++ks) {
      bf16x8 vf = *(const bf16x8*)(vb + (size_t)(dt * 16 + (lane & 15)) * Ss + t0 + ks * 32 + (lane >> 4) * 8);
      acc[dt] = __builtin_amdgcn_mfma_f32_16x16x32_bf16(pf[ks], vf, acc[dt], 0, 0, 0);
    }

  int b = bh >> 4, h = bh & 15;
  float sc[4];
#pragma unroll
  for (int r = 0; r < 4; ++r)
    sc[r] = invn[(size_t)bh * Ss + t0 + w * 16 + (lane >> 4) * 4 + r];
#pragma unroll
  for (int dt = 0; dt < 4; ++dt)
#pragma unroll
    for (int r = 0; r < 4; ++r) {
      int t = t0 + w * 16 + (lane >> 4) * 4 + r;
      size_t m = (size_t)b * Ss + t;
      ctx[m * Dm + h * Hd + dt * 16 + (lane & 15)] = f2bf(acc[dt][r] * sc[r]);
    }
}

// ---------- launch ----------
extern "C" void kernel_launch(void* const* d_in, const int* in_sizes, int n_in,
                              void* d_out, int out_size, void* d_ws, size_t ws_size,
                              hipStream_t stream) {
  const float* x   = (const float*)d_in[0];
  const float* Wqk = (const float*)d_in[1];
  const float* bqk = (const float*)d_in[2];
  const float* Wv  = (const float*)d_in[3];
  const float* bv  = (const float*)d_in[4];
  const float* Wn  = (const float*)d_in[5];
  const float* bn  = (const float*)d_in[6];
  const float* Wo  = (const float*)d_in[7];
  const float* bo  = (const float*)d_in[8];

  char* ws = (char*)d_ws;
  size_t off = 0;
  unsigned short* xb    = (unsigned short*)(ws + off); off += (size_t)Mtot * Dm * 2;          // 8 MB
  unsigned short* wprojT= (unsigned short*)(ws + off); off += (size_t)3072 * 1024 * 2;        // 6 MB
  unsigned short* woT   = (unsigned short*)(ws + off); off += (size_t)1024 * 1024 * 2;        // 2 MB
  unsigned short* qbuf  = (unsigned short*)(ws + off); off += (size_t)Bb * Hh * Ss * Hd * 2;  // 8 MB
  unsigned short* kbuf  = (unsigned short*)(ws + off); off += (size_t)Bb * Hh * Ss * Hd * 2;  // 8 MB
  unsigned short* ktbuf = (unsigned short*)(ws + off); off += (size_t)Bb * Hh * Ss * Hd * 2;  // 8 MB
  unsigned short* vbuf  = (unsigned short*)(ws + off); off += (size_t)Bb * Hh * Ss * Hd * 2;  // 8 MB
  float* invn           = (float*)(ws + off);          off += (size_t)Bb * Hh * Ss * 4;       // 256 KB
  unsigned short* G     = (unsigned short*)(ws + off); off += (size_t)Bb * Hh * NCH * 4096 * 2; // 8 MB
  unsigned short* Sp    = (unsigned short*)(ws + off); off += (size_t)Bb * Hh * NCH * 4096 * 2; // 8 MB
  unsigned short* ctx   = xb;  // alias: xb dead after fused projection GEMM

  // 1) weight transposes (bf16, [N][K])
  k_transpose_conv<<<dim3(2048 / 32, 1024 / 32), dim3(32, 8), 0, stream>>>(Wqk, wprojT, 1024, 2048);
  k_transpose_conv<<<dim3(1024 / 32, 1024 / 32), dim3(32, 8), 0, stream>>>(Wv, wprojT + (size_t)2048 * 1024, 1024, 1024);
  k_transpose_conv<<<dim3(1024 / 32, 1024 / 32), dim3(32, 8), 0, stream>>>(Wo, woT, 1024, 1024);

  // 2) n path + x conversion
  k_n_proj<<<Mtot / 4, 256, 0, stream>>>(x, Wn, bn, invn, xb);

  // 3) fused q/k/v projections (N = 3072), 128x128 m97 structure (768 blocks)
  k_gemm_proj<<<dim3(3072 / 128, Mtot / 128), 256, 0, stream>>>(
      xb, wprojT, bqk, bv, qbuf, kbuf, ktbuf, vbuf, Mtot, 3072, 1024);

  // 4) attention = parallel gram + parallel prefix + per-chunk
  k_gram<<<dim3(NCH, Bb * Hh), 64, 0, stream>>>(vbuf, ktbuf, G);
  k_prefix<<<(Bb * Hh * 4096) / 256, 256, 0, stream>>>(G, Sp);
  k_chunk_attn<<<dim3(NCH, Bb * Hh), 256, 0, stream>>>(qbuf, kbuf, vbuf, Sp, invn, ctx);

  // 5) output projection -> f32 d_out, 64x128 tile (512 blocks, 2/CU)
  k_gemm_o<<<dim3(1024 / 128, Mtot / 64), 256, 0, stream>>>(ctx, woT, bo, (float*)d_out);
}

// Round 7
// 108.918 us; speedup vs baseline: 1.9592x; 1.0336x over previous
//
#include <hip/hip_runtime.h>
#include <hip/hip_bf16.h>

// ---------- problem constants ----------
constexpr int Bb   = 2;
constexpr int Ss   = 2048;
constexpr int Dm   = 1024;
constexpr int Hh   = 16;
constexpr int Hd   = 64;
constexpr int Mtot = Bb * Ss;      // 4096
constexpr int NCH  = Ss / 64;      // 32 chunks of 64

typedef __bf16 bf16x8 __attribute__((ext_vector_type(8)));
typedef float  f32x4  __attribute__((ext_vector_type(4)));
typedef __attribute__((address_space(1))) unsigned int u32_as1;
typedef __attribute__((address_space(3))) unsigned int u32_as3;

__device__ __forceinline__ void gload_lds16(const void* g, void* l) {
  __builtin_amdgcn_global_load_lds((const u32_as1*)g, (u32_as3*)l, 16, 0, 0);
}

__device__ __forceinline__ unsigned short f2bf(float f) {
  union { float f; unsigned u; } x; x.f = f;
  unsigned r = x.u + 0x7fffu + ((x.u >> 16) & 1u);   // RNE
  return (unsigned short)(r >> 16);
}

__device__ __forceinline__ float bf2f(unsigned short s) {
  union { unsigned u; float f; } x; x.u = ((unsigned)s) << 16;
  return x.f;
}

// ---------- transpose-convert all three W [K,N] f32 -> Wt [N,K] bf16 in one launch ----------
// z = 0: Wqk (N=2048), z = 1: Wv (N=1024), z = 2: Wo (N=1024). K=1024 for all.
__global__ void k_transpose_all(const float* __restrict__ W0, const float* __restrict__ W1,
                                const float* __restrict__ W2, unsigned short* __restrict__ D0,
                                unsigned short* __restrict__ D1, unsigned short* __restrict__ D2) {
  __shared__ float t[32][33];
  int z = blockIdx.z;
  int N = (z == 0) ? 2048 : 1024;
  int n0 = blockIdx.x * 32, k0 = blockIdx.y * 32;
  if (n0 >= N) return;                        // block-uniform early exit
  const float* W = (z == 0) ? W0 : (z == 1) ? W1 : W2;
  unsigned short* Wt = (z == 0) ? D0 : (z == 1) ? D1 : D2;
  int tx = threadIdx.x, ty = threadIdx.y;
#pragma unroll
  for (int j = 0; j < 32; j += 8)
    t[ty + j][tx] = W[(size_t)(k0 + ty + j) * N + n0 + tx];
  __syncthreads();
#pragma unroll
  for (int j = 0; j < 32; j += 8)
    Wt[(size_t)(n0 + ty + j) * 1024 + k0 + tx] = f2bf(t[tx][ty + j]);
}

// ---------- n projection + x->bf16 convert ----------
// invn[b,h,s] = exp(-(x @ Wn + bn)); xb[m][k] = bf16(x)
__global__ void k_n_proj(const float* __restrict__ x, const float* __restrict__ Wn,
                         const float* __restrict__ bn, float* __restrict__ invn,
                         unsigned short* __restrict__ xb) {
  __shared__ float xl[4][1024];
  int tid = threadIdx.x, w = tid >> 6, lane = tid & 63;
  int row = blockIdx.x * 4 + w;                       // [0, 4096)
  const float4* x4 = (const float4*)(x + (size_t)row * Dm);
  ushort4* xb4 = (ushort4*)(xb + (size_t)row * Dm);
#pragma unroll
  for (int j = 0; j < 4; ++j) {
    float4 v = x4[j * 64 + lane];
    *(float4*)&xl[w][(j * 64 + lane) * 4] = v;
    ushort4 o;
    o.x = f2bf(v.x); o.y = f2bf(v.y); o.z = f2bf(v.z); o.w = f2bf(v.w);
    xb4[j * 64 + lane] = o;
  }
  __syncthreads();
  const float4* Wn4 = (const float4*)Wn;
  f32x4 sum = {0.f, 0.f, 0.f, 0.f};
#pragma unroll 4
  for (int j = 0; j < 64; ++j) {
    float xv = xl[w][j * 16 + (lane >> 2)];
    float4 wv = Wn4[j * 64 + lane];
    sum[0] += xv * wv.x; sum[1] += xv * wv.y; sum[2] += xv * wv.z; sum[3] += xv * wv.w;
  }
#pragma unroll
  for (int m = 4; m < 64; m <<= 1) {
    sum[0] += __shfl_xor(sum[0], m);
    sum[1] += __shfl_xor(sum[1], m);
    sum[2] += __shfl_xor(sum[2], m);
    sum[3] += __shfl_xor(sum[3], m);
  }
  if (lane < 4) {
    int b = row >> 11, s = row & 2047;
#pragma unroll
    for (int e = 0; e < 4; ++e) {
      int h = lane * 4 + e;
      float nv = sum[e] + bn[h];
      invn[((size_t)(b * Hh + h)) * Ss + s] = expf(-nv);
    }
  }
}

// ---------- fused projection GEMM (m97 structure): A[M,K] x BT[N,K] ----------
// N=3072: n<1024 -> q [bh,t,d]; 1024<=n<2048 -> k [bh,t,d] + kT [bh,d,t]; n>=2048 -> vT [bh,d,t]
// launch_bounds (256,4): 4 blocks/CU (LDS 32KB x 4 = 128KB, VGPR<=128) for cross-block
// overlap of the per-block barrier drain.
__global__ __launch_bounds__(256, 4) void k_gemm_proj(
    const unsigned short* __restrict__ A, const unsigned short* __restrict__ BT,
    const float* __restrict__ bias0, const float* __restrict__ bias1,
    void* __restrict__ out0, void* __restrict__ out1, void* __restrict__ out2,
    void* __restrict__ out3, int M, int N, int K) {
  __shared__ __align__(16) unsigned short As[128 * 64];
  __shared__ __align__(16) unsigned short Bs[128 * 64];
  int tid = threadIdx.x, w = tid >> 6, lane = tid & 63;
  int m0 = blockIdx.y * 128, n0 = blockIdx.x * 128;
  int wm = w >> 1, wn = w & 1;
  f32x4 acc[4][4] = {};

  for (int kt = 0; kt < (K >> 6); ++kt) {
#pragma unroll
    for (int i = 0; i < 4; ++i) {
      int lin = i * 2048 + w * 512 + lane * 8;
      int r = lin >> 6, c = lin & 63;
      gload_lds16(A + (size_t)(m0 + r) * K + kt * 64 + c, As + i * 2048 + w * 512);
    }
#pragma unroll
    for (int i = 0; i < 4; ++i) {
      int lin = i * 2048 + w * 512 + lane * 8;
      int r = lin >> 6, c = lin & 63;
      gload_lds16(BT + (size_t)(n0 + r) * K + kt * 64 + c, Bs + i * 2048 + w * 512);
    }
    __syncthreads();
#pragma unroll
    for (int ks = 0; ks < 2; ++ks) {
      bf16x8 af[4], bfr[4];
#pragma unroll
      for (int mt = 0; mt < 4; ++mt)
        af[mt] = *(const bf16x8*)(As + (wm * 64 + mt * 16 + (lane & 15)) * 64 + ks * 32 + (lane >> 4) * 8);
#pragma unroll
      for (int nt = 0; nt < 4; ++nt)
        bfr[nt] = *(const bf16x8*)(Bs + (wn * 64 + nt * 16 + (lane & 15)) * 64 + ks * 32 + (lane >> 4) * 8);
#pragma unroll
      for (int mt = 0; mt < 4; ++mt)
#pragma unroll
        for (int nt = 0; nt < 4; ++nt)
          acc[mt][nt] = __builtin_amdgcn_mfma_f32_16x16x32_bf16(af[mt], bfr[nt], acc[mt][nt], 0, 0, 0);
    }
    __syncthreads();
  }

#pragma unroll
  for (int mt = 0; mt < 4; ++mt) {
#pragma unroll
    for (int nt = 0; nt < 4; ++nt) {
      int n = n0 + wn * 64 + nt * 16 + (lane & 15);
      int tbase = m0 + wm * 64 + mt * 16 + (lane >> 4) * 4;
      int region = n >> 10;                 // wave-uniform (boundaries % 128 == 0)
      int h = (n >> 6) & 15, d = n & 63;
      int b = tbase >> 11, t = tbase & 2047;
      float bb = (region < 2) ? bias0[n] : bias1[n - 2048];
      if (region == 0) {
        unsigned short* qp = (unsigned short*)out0;
#pragma unroll
        for (int r = 0; r < 4; ++r)
          qp[(((size_t)(b * Hh + h)) * Ss + t + r) * Hd + d] = f2bf(acc[mt][nt][r] + bb);
      } else if (region == 1) {
        unsigned short* kp = (unsigned short*)out1;
#pragma unroll
        for (int r = 0; r < 4; ++r)
          kp[(((size_t)(b * Hh + h)) * Ss + t + r) * Hd + d] = f2bf(acc[mt][nt][r] + bb);
        ushort4 o;
        o.x = f2bf(acc[mt][nt][0] + bb);
        o.y = f2bf(acc[mt][nt][1] + bb);
        o.z = f2bf(acc[mt][nt][2] + bb);
        o.w = f2bf(acc[mt][nt][3] + bb);
        *(ushort4*)((unsigned short*)out2 + ((size_t)(b * Hh + h) * Hd + d) * Ss + t) = o;
      } else {
        ushort4 o;
        o.x = f2bf(acc[mt][nt][0] + bb);
        o.y = f2bf(acc[mt][nt][1] + bb);
        o.z = f2bf(acc[mt][nt][2] + bb);
        o.w = f2bf(acc[mt][nt][3] + bb);
        *(ushort4*)((unsigned short*)out3 + ((size_t)(b * Hh + h) * Hd + d) * Ss + t) = o;
      }
    }
  }
}

// ---------- output GEMM: 64x128 tile (512 blocks); 5 blocks/CU ----------
// out[m][1024] f32 = ctx[m][k] @ WoT[n][k] + bo
__global__ __launch_bounds__(256, 5) void k_gemm_o(
    const unsigned short* __restrict__ A, const unsigned short* __restrict__ BT,
    const float* __restrict__ bias, float* __restrict__ out) {
  constexpr int K = 1024, N = 1024;
  __shared__ __align__(16) unsigned short As[64 * 64];
  __shared__ __align__(16) unsigned short Bs[128 * 64];
  int tid = threadIdx.x, w = tid >> 6, lane = tid & 63;
  int m0 = blockIdx.y * 64, n0 = blockIdx.x * 128;
  int wm = w >> 1, wn = w & 1;    // waves: 2 over M(32 each), 2 over N(64 each)
  f32x4 acc[2][4] = {};

  for (int kt = 0; kt < (K >> 6); ++kt) {
#pragma unroll
    for (int i = 0; i < 2; ++i) {
      int lin = i * 2048 + w * 512 + lane * 8;
      int r = lin >> 6, c = lin & 63;
      gload_lds16(A + (size_t)(m0 + r) * K + kt * 64 + c, As + i * 2048 + w * 512);
    }
#pragma unroll
    for (int i = 0; i < 4; ++i) {
      int lin = i * 2048 + w * 512 + lane * 8;
      int r = lin >> 6, c = lin & 63;
      gload_lds16(BT + (size_t)(n0 + r) * K + kt * 64 + c, Bs + i * 2048 + w * 512);
    }
    __syncthreads();
#pragma unroll
    for (int ks = 0; ks < 2; ++ks) {
      bf16x8 af[2], bfr[4];
#pragma unroll
      for (int mt = 0; mt < 2; ++mt)
        af[mt] = *(const bf16x8*)(As + (wm * 32 + mt * 16 + (lane & 15)) * 64 + ks * 32 + (lane >> 4) * 8);
#pragma unroll
      for (int nt = 0; nt < 4; ++nt)
        bfr[nt] = *(const bf16x8*)(Bs + (wn * 64 + nt * 16 + (lane & 15)) * 64 + ks * 32 + (lane >> 4) * 8);
#pragma unroll
      for (int mt = 0; mt < 2; ++mt)
#pragma unroll
        for (int nt = 0; nt < 4; ++nt)
          acc[mt][nt] = __builtin_amdgcn_mfma_f32_16x16x32_bf16(af[mt], bfr[nt], acc[mt][nt], 0, 0, 0);
    }
    __syncthreads();
  }

#pragma unroll
  for (int mt = 0; mt < 2; ++mt) {
#pragma unroll
    for (int nt = 0; nt < 4; ++nt) {
      int n = n0 + wn * 64 + nt * 16 + (lane & 15);
      int m = m0 + wm * 32 + mt * 16 + (lane >> 4) * 4;
      float bb = bias[n];
#pragma unroll
      for (int r = 0; r < 4; ++r)
        out[(size_t)(m + r) * N + n] = acc[mt][nt][r] + bb;
    }
  }
}

// ---------- pass A1: per-chunk gram  G_j[dv][d] = sum_{s in chunk j} v[s][dv]*k[s][d] ----------
__global__ __launch_bounds__(64) void k_gram(
    const unsigned short* __restrict__ vT, const unsigned short* __restrict__ kT,
    unsigned short* __restrict__ G) {
  int lane = threadIdx.x;
  int j = blockIdx.x, bh = blockIdx.y;
  int t0 = j * 64;
  const unsigned short* vb = vT + (size_t)bh * Hd * Ss;
  const unsigned short* kb = kT + (size_t)bh * Hd * Ss;
  unsigned short* g = G + ((size_t)bh * NCH + j) * 4096;

  bf16x8 af[4][2], bfr[4][2];
#pragma unroll
  for (int mt = 0; mt < 4; ++mt)
#pragma unroll
    for (int ks = 0; ks < 2; ++ks) {
      af[mt][ks]  = *(const bf16x8*)(vb + (size_t)(mt * 16 + (lane & 15)) * Ss + t0 + ks * 32 + (lane >> 4) * 8);
      bfr[mt][ks] = *(const bf16x8*)(kb + (size_t)(mt * 16 + (lane & 15)) * Ss + t0 + ks * 32 + (lane >> 4) * 8);
    }
  f32x4 acc[4][4] = {};
#pragma unroll
  for (int mt = 0; mt < 4; ++mt)
#pragma unroll
    for (int nt = 0; nt < 4; ++nt)
#pragma unroll
      for (int ks = 0; ks < 2; ++ks)
        acc[mt][nt] = __builtin_amdgcn_mfma_f32_16x16x32_bf16(af[mt][ks], bfr[nt][ks], acc[mt][nt], 0, 0, 0);
#pragma unroll
  for (int mt = 0; mt < 4; ++mt)
#pragma unroll
    for (int nt = 0; nt < 4; ++nt)
#pragma unroll
      for (int r = 0; r < 4; ++r)
        g[(mt * 16 + (lane >> 4) * 4 + r) * 64 + nt * 16 + (lane & 15)] = f2bf(acc[mt][nt][r]);
}

// ---------- pass A2: exclusive prefix over chunks ----------
__global__ __launch_bounds__(256) void k_prefix(
    const unsigned short* __restrict__ G, unsigned short* __restrict__ Sp) {
  int gidx = blockIdx.x * 256 + threadIdx.x;   // 32 bh * 4096 elems
  int bh = gidx >> 12, e = gidx & 4095;
  const unsigned short* gp = G + (size_t)bh * NCH * 4096 + e;
  unsigned short* sp = Sp + (size_t)bh * NCH * 4096 + e;
  float acc = 0.f;
#pragma unroll 8
  for (int j = 0; j < NCH; ++j) {
    sp[(size_t)j * 4096] = f2bf(acc);
    acc += bf2f(gp[(size_t)j * 4096]);
  }
}

// ---------- pass B: per-chunk attention  ctx = (Q@S'^T + tril(QK^T)@V) * invn ----------
__global__ __launch_bounds__(256, 6) void k_chunk_attn(
    const unsigned short* __restrict__ q, const unsigned short* __restrict__ k,
    const unsigned short* __restrict__ vT, const unsigned short* __restrict__ Sp,
    const float* __restrict__ invn, unsigned short* __restrict__ ctx) {
  __shared__ __align__(16) unsigned short P[4 * 16 * 64];
  int tid = threadIdx.x, w = tid >> 6, lane = tid & 63;
  int j = blockIdx.x, bh = blockIdx.y;
  int t0 = j * 64;
  const unsigned short* qb = q + (size_t)bh * Ss * Hd;
  const unsigned short* kb = k + (size_t)bh * Ss * Hd;
  const unsigned short* vb = vT + (size_t)bh * Hd * Ss;
  const unsigned short* sp = Sp + ((size_t)bh * NCH + j) * 4096;

  bf16x8 qf[2];
#pragma unroll
  for (int ks = 0; ks < 2; ++ks)
    qf[ks] = *(const bf16x8*)(qb + (size_t)(t0 + w * 16 + (lane & 15)) * Hd + ks * 32 + (lane >> 4) * 8);

  f32x4 acc[4] = {};
#pragma unroll
  for (int nt = 0; nt < 4; ++nt)
#pragma unroll
    for (int ks = 0; ks < 2; ++ks) {
      bf16x8 sf = *(const bf16x8*)(sp + (nt * 16 + (lane & 15)) * 64 + ks * 32 + (lane >> 4) * 8);
      acc[nt] = __builtin_amdgcn_mfma_f32_16x16x32_bf16(qf[ks], sf, acc[nt], 0, 0, 0);
    }

  f32x4 sacc[4] = {};
#pragma unroll
  for (int nt = 0; nt < 4; ++nt)
#pragma unroll
    for (int ks = 0; ks < 2; ++ks) {
      bf16x8 kf = *(const bf16x8*)(kb + (size_t)(t0 + nt * 16 + (lane & 15)) * Hd + ks * 32 + (lane >> 4) * 8);
      sacc[nt] = __builtin_amdgcn_mfma_f32_16x16x32_bf16(qf[ks], kf, sacc[nt], 0, 0, 0);
    }

#pragma unroll
  for (int nt = 0; nt < 4; ++nt)
#pragma unroll
    for (int r = 0; r < 4; ++r) {
      int row = (lane >> 4) * 4 + r;
      int s_local = nt * 16 + (lane & 15);
      float vv = (s_local <= w * 16 + row) ? sacc[nt][r] : 0.f;
      int cb = s_local * 2;
      int byte = w * 2048 + row * 128 + (cb ^ ((row & 7) << 4));
      *(unsigned short*)((char*)P + byte) = f2bf(vv);
    }
  asm volatile("" ::: "memory");

  bf16x8 pf[2];
#pragma unroll
  for (int ks = 0; ks < 2; ++ks) {
    int prow = lane & 15;
    int pcb = (ks * 32 + (lane >> 4) * 8) * 2;
    pf[ks] = *(const bf16x8*)((char*)P + w * 2048 + prow * 128 + (pcb ^ ((prow & 7) << 4)));
  }
#pragma unroll
  for (int dt = 0; dt < 4; ++dt)
#pragma unroll
    for (int ks = 0; ks < 2; ++ks) {
      bf16x8 vf = *(const bf16x8*)(vb + (size_t)(dt * 16 + (lane & 15)) * Ss + t0 + ks * 32 + (lane >> 4) * 8);
      acc[dt] = __builtin_amdgcn_mfma_f32_16x16x32_bf16(pf[ks], vf, acc[dt], 0, 0, 0);
    }

  int b = bh >> 4, h = bh & 15;
  float sc[4];
#pragma unroll
  for (int r = 0; r < 4; ++r)
    sc[r] = invn[(size_t)bh * Ss + t0 + w * 16 + (lane >> 4) * 4 + r];
#pragma unroll
  for (int dt = 0; dt < 4; ++dt)
#pragma unroll
    for (int r = 0; r < 4; ++r) {
      int t = t0 + w * 16 + (lane >> 4) * 4 + r;
      size_t m = (size_t)b * Ss + t;
      ctx[m * Dm + h * Hd + dt * 16 + (lane & 15)] = f2bf(acc[dt][r] * sc[r]);
    }
}

// ---------- launch ----------
extern "C" void kernel_launch(void* const* d_in, const int* in_sizes, int n_in,
                              void* d_out, int out_size, void* d_ws, size_t ws_size,
                              hipStream_t stream) {
  const float* x   = (const float*)d_in[0];
  const float* Wqk = (const float*)d_in[1];
  const float* bqk = (const float*)d_in[2];
  const float* Wv  = (const float*)d_in[3];
  const float* bv  = (const float*)d_in[4];
  const float* Wn  = (const float*)d_in[5];
  const float* bn  = (const float*)d_in[6];
  const float* Wo  = (const float*)d_in[7];
  const float* bo  = (const float*)d_in[8];

  char* ws = (char*)d_ws;
  size_t off = 0;
  unsigned short* xb    = (unsigned short*)(ws + off); off += (size_t)Mtot * Dm * 2;          // 8 MB
  unsigned short* wprojT= (unsigned short*)(ws + off); off += (size_t)3072 * 1024 * 2;        // 6 MB
  unsigned short* woT   = (unsigned short*)(ws + off); off += (size_t)1024 * 1024 * 2;        // 2 MB
  unsigned short* qbuf  = (unsigned short*)(ws + off); off += (size_t)Bb * Hh * Ss * Hd * 2;  // 8 MB
  unsigned short* kbuf  = (unsigned short*)(ws + off); off += (size_t)Bb * Hh * Ss * Hd * 2;  // 8 MB
  unsigned short* ktbuf = (unsigned short*)(ws + off); off += (size_t)Bb * Hh * Ss * Hd * 2;  // 8 MB
  unsigned short* vbuf  = (unsigned short*)(ws + off); off += (size_t)Bb * Hh * Ss * Hd * 2;  // 8 MB
  float* invn           = (float*)(ws + off);          off += (size_t)Bb * Hh * Ss * 4;       // 256 KB
  unsigned short* G     = (unsigned short*)(ws + off); off += (size_t)Bb * Hh * NCH * 4096 * 2; // 8 MB
  unsigned short* Sp    = (unsigned short*)(ws + off); off += (size_t)Bb * Hh * NCH * 4096 * 2; // 8 MB
  unsigned short* ctx   = xb;  // alias: xb dead after fused projection GEMM

  // 1) weight transposes (bf16, [N][K]) in one launch
  k_transpose_all<<<dim3(2048 / 32, 1024 / 32, 3), dim3(32, 8), 0, stream>>>(
      Wqk, Wv, Wo, wprojT, wprojT + (size_t)2048 * 1024, woT);

  // 2) n path + x conversion
  k_n_proj<<<Mtot / 4, 256, 0, stream>>>(x, Wn, bn, invn, xb);

  // 3) fused q/k/v projections (N = 3072), 128x128 m97 structure (768 blocks, 4/CU)
  k_gemm_proj<<<dim3(3072 / 128, Mtot / 128), 256, 0, stream>>>(
      xb, wprojT, bqk, bv, qbuf, kbuf, ktbuf, vbuf, Mtot, 3072, 1024);

  // 4) attention = parallel gram + parallel prefix + per-chunk
  k_gram<<<dim3(NCH, Bb * Hh), 64, 0, stream>>>(vbuf, ktbuf, G);
  k_prefix<<<(Bb * Hh * 4096) / 256, 256, 0, stream>>>(G, Sp);
  k_chunk_attn<<<dim3(NCH, Bb * Hh), 256, 0, stream>>>(qbuf, kbuf, vbuf, Sp, invn, ctx);

  // 5) output projection -> f32 d_out, 64x128 tile (512 blocks, 5/CU)
  k_gemm_o<<<dim3(1024 / 128, Mtot / 64), 256, 0, stream>>>(ctx, woT, bo, (float*)d_out);
}